// Round 7
// baseline (748.637 us; speedup 1.0000x reference)
//
#include <hip/hip_runtime.h>

#define B_    64
#define NI    2048
#define DK    16
#define NO    32
#define DOUT  32
#define EPSQ  1e-7f

typedef unsigned u32x2 __attribute__((ext_vector_type(2)));
typedef unsigned u32x4 __attribute__((ext_vector_type(4)));
typedef float    f32x4 __attribute__((ext_vector_type(4)));

constexpr int BH   = 32;   // b's per half-pipeline (U_half = 134 MB < 256 MB L3)
constexpr int PSEG = 32;   // i-segments (partials + mid blocking)

// ---------- helpers ----------
__device__ __forceinline__ unsigned pack2_bf16(float a, float b) {
    unsigned ua = __float_as_uint(a);
    unsigned ub = __float_as_uint(b);
    ua = (ua + 0x7fffu + ((ua >> 16) & 1u)) >> 16;   // RNE
    ub = (ub + 0x7fffu + ((ub >> 16) & 1u)) >> 16;
    return ua | (ub << 16);
}
__device__ __forceinline__ float bf_lo(unsigned w) { return __uint_as_float(w << 16); }
__device__ __forceinline__ float bf_hi(unsigned w) { return __uint_as_float(w & 0xffff0000u); }

// ============================================================
// u_hat layout (bf16/ushort), b indexed LOCALLY within the half:
// idx = (((bl*NI + i)*4 + j)*NO + o)*8 + e,  d = j*8+e
// per (bl,i): 4 rows of 256 ushorts = 2KB contiguous.
// ============================================================

// ------------------------------------------------------------
// uhat_half: block = (i, o-half). 512 threads.
// t -> o2 = t&15, q = (t>>4)&7 (d-quad), bh = t>>7 (8 b's each).
// W tile 16 o staged to LDS with NT loads (don't evict U from L3).
// Strides: per-o 545, per-q 68 -> <=2-way LDS read conflict (free).
// Each W float4 reused across 4 b's (acc[4][4]) -> 4x less LDS read.
// 37 KB LDS, natural VGPR (NO forced min-occupancy - round-4 lesson).
// U stores are REGULAR (cached) so U_half stays L3-resident for readers.
// Arithmetic order per u identical to round-2/5 kernel (same absmax).
// ------------------------------------------------------------
__global__ __launch_bounds__(512)
void uhat_half(const float* __restrict__ x, const float* __restrict__ W,
               ushort* __restrict__ U, int b0)
{
    __shared__ float Ws[16 * 545];   // 34880 B
    __shared__ float xs[BH * DK];    // 2048 B
    const int bx = blockIdx.x;
    const int i  = bx >> 1;
    const int oh = bx & 1;
    const int t  = threadIdx.x;

    // stage x[b0 .. b0+31, i, 0:16] (2 KB)
    if (t < 128) {
        const int b = t >> 2, k4 = t & 3;
        float4 v = *(const float4*)(x + ((size_t)(b0 + b) * NI + i) * DK + k4 * 4);
        *(float4*)&xs[b * DK + k4 * 4] = v;
    }

    // stage W[oh*16 .. +15, i, :, :] (32 KB), NT, coalesced
    #pragma unroll
    for (int pp = 0; pp < 4; ++pp) {
        const int p  = t + 512 * pp;     // 0..2047
        const int oo = p >> 7;           // 0..15
        const int cc = p & 127;          // float4 within o-row
        const int qq = cc >> 4;          // q-subrow
        const int kk = cc & 15;
        const f32x4* wp = (const f32x4*)(W + ((size_t)(oh * 16 + oo) * NI + i) * (DOUT * DK));
        f32x4 v = __builtin_nontemporal_load(wp + cc);
        *(f32x4*)&Ws[oo * 545 + qq * 68 + kk * 4] = v;
    }

    const int o2 = t & 15;
    const int q  = (t >> 4) & 7;      // d = 4q .. 4q+3
    const int bh = t >> 7;            // 0..3 -> 8 b's each

    __syncthreads();

    const int j = q >> 1, half = q & 1;
    const int o = oh * 16 + o2;
    const float* wrow = &Ws[o2 * 545 + q * 68];   // [16*dl + 4*k4]

    #pragma unroll
    for (int bg = 0; bg < 2; ++bg) {
        const int bl0 = bh * 8 + bg * 4;
        float acc[4][4];
        #pragma unroll
        for (int bv = 0; bv < 4; ++bv)
            #pragma unroll
            for (int dl = 0; dl < 4; ++dl) acc[bv][dl] = 0.f;

        #pragma unroll
        for (int k4 = 0; k4 < 4; ++k4) {
            float4 xr[4];
            #pragma unroll
            for (int bv = 0; bv < 4; ++bv)
                xr[bv] = *(const float4*)&xs[(bl0 + bv) * DK + k4 * 4];  // broadcast
            #pragma unroll
            for (int dl = 0; dl < 4; ++dl) {
                const float4 w4 = *(const float4*)&wrow[16 * dl + 4 * k4];
                #pragma unroll
                for (int bv = 0; bv < 4; ++bv) {
                    float a = acc[bv][dl];
                    a = fmaf(w4.x, xr[bv].x, a);
                    a = fmaf(w4.y, xr[bv].y, a);
                    a = fmaf(w4.z, xr[bv].z, a);
                    a = fmaf(w4.w, xr[bv].w, a);
                    acc[bv][dl] = a;
                }
            }
        }

        #pragma unroll
        for (int bv = 0; bv < 4; ++bv) {
            const int bl = bl0 + bv;
            u32x2 pk;
            pk.x = pack2_bf16(acc[bv][0], acc[bv][1]);
            pk.y = pack2_bf16(acc[bv][2], acc[bv][3]);
            const size_t off = ((((size_t)bl * NI + i) * 4 + j) * NO + o) * 8 + half * 4;
            *(u32x2*)(U + off) = pk;      // regular store -> L3-resident
        }
    }
}

// ============================================================
// sum_u_half: P0[bl,iseg,o,d] = (1/32)*sum_{i in seg} u. Block = (bl, iseg).
// 256 threads; c = t&127 owns one uint4 column; i-parity halves; LDS merge.
// Regular loads (want L3 hits).
// ============================================================
__global__ __launch_bounds__(256)
void sum_u_half(const ushort* __restrict__ U, float* __restrict__ P0)
{
    __shared__ float red[128 * 9];     // pad 9 -> conflict-free
    const int t    = threadIdx.x;
    const int bl   = blockIdx.x >> 5;
    const int iseg = blockIdx.x & 31;
    const int c    = t & 127;
    const int half = t >> 7;

    float acc[8];
    #pragma unroll
    for (int k = 0; k < 8; ++k) acc[k] = 0.f;

    const u32x4* up = (const u32x4*)U
        + ((size_t)bl * NI + (size_t)iseg * (NI / PSEG) + half) * 128 + c;

    #pragma unroll 8
    for (int it = 0; it < (NI / PSEG) / 2; ++it) {
        u32x4 w = *up;
        up += 256;
        acc[0] += bf_lo(w.x); acc[1] += bf_hi(w.x);
        acc[2] += bf_lo(w.y); acc[3] += bf_hi(w.y);
        acc[4] += bf_lo(w.z); acc[5] += bf_hi(w.z);
        acc[6] += bf_lo(w.w); acc[7] += bf_hi(w.w);
    }

    if (half == 1) {
        #pragma unroll
        for (int k = 0; k < 8; ++k) red[c * 9 + k] = acc[k];
    }
    __syncthreads();
    if (half == 0) {
        #pragma unroll
        for (int k = 0; k < 8; ++k) acc[k] = (acc[k] + red[c * 9 + k]) * 0.03125f;

        const int o = c & 31, j = c >> 5;
        float* sp = P0 + ((size_t)(bl * PSEG + iseg)) * 1024 + o * 32 + j * 8;
        float4 lo = {acc[0], acc[1], acc[2], acc[3]};
        float4 hi = {acc[4], acc[5], acc[6], acc[7]};
        *(float4*)sp = lo;
        *(float4*)(sp + 4) = hi;
    }
}

// ============================================================
// rsq: reduce partials -> s, squash -> v, accumulate running Vsum.
// R==1: VsOut = squash(sum P).  R==2: VsOut = VsIn + squash(sum P).
// One thread per (bl,o,d); 32-lane shfl reduce for the d-norm.
// Runs ONCE per round (128 blocks) instead of inside every mid block.
// ============================================================
template<int R>
__global__ __launch_bounds__(256)
void rsq(const float* __restrict__ P, const float* __restrict__ VsIn,
         float* __restrict__ VsOut)
{
    const int g    = blockIdx.x * 256 + threadIdx.x;   // bl*1024 + o*32 + d
    const int bl   = g >> 10, slot = g & 1023;
    float a = 0.f;
    for (int is = 0; is < PSEG; ++is)
        a += P[((size_t)(bl * PSEG + is)) * 1024 + slot];

    float sq = a * a;
    #pragma unroll
    for (int msk = 16; msk >= 1; msk >>= 1) sq += __shfl_xor(sq, msk);
    const float sc = sq / (1.f + sq) * rsqrtf(sq + EPSQ);
    const float v  = a * sc;
    VsOut[g] = (R == 1) ? v : v + VsIn[g];
}

// ---------- per-i routing math: logit -> softmax over o -> accumulate ----------
__device__ __forceinline__ void mid_proc(const u32x4 c0, const u32x4 c1,
                                         const float* vs, float* sacc)
{
    float lp = 0.f;
    #pragma unroll
    for (int wi = 0; wi < 4; ++wi) {
        lp = fmaf(vs[2*wi],         bf_lo(c0[wi]), lp);
        lp = fmaf(vs[2*wi + 1],     bf_hi(c0[wi]), lp);
        lp = fmaf(vs[8 + 2*wi],     bf_lo(c1[wi]), lp);
        lp = fmaf(vs[8 + 2*wi + 1], bf_hi(c1[wi]), lp);
    }
    lp += __shfl_xor(lp, 32);    // full logit on all 64 lanes

    float mx = lp;
    #pragma unroll
    for (int msk = 16; msk >= 1; msk >>= 1) mx = fmaxf(mx, __shfl_xor(mx, msk));
    const float e = __expf(lp - mx);
    float ss = e;
    #pragma unroll
    for (int msk = 16; msk >= 1; msk >>= 1) ss += __shfl_xor(ss, msk);
    const float cc = e / ss;

    #pragma unroll
    for (int wi = 0; wi < 4; ++wi) {
        sacc[2*wi]         = fmaf(cc, bf_lo(c0[wi]), sacc[2*wi]);
        sacc[2*wi + 1]     = fmaf(cc, bf_hi(c0[wi]), sacc[2*wi + 1]);
        sacc[8 + 2*wi]     = fmaf(cc, bf_lo(c1[wi]), sacc[8 + 2*wi]);
        sacc[8 + 2*wi + 1] = fmaf(cc, bf_hi(c1[wi]), sacc[8 + 2*wi + 1]);
    }
}

// ============================================================
// mid_half: one routing pass over U (half). Block = (bl, iseg of 64 i).
// 256 thr = 4 waves; full wave per i (lane = o, dh); dual 8-i streams.
// Prologue: vs[16] = 4 float4 loads from precomputed Vs (no fan-in).
// Epilogue: LDS-swizzled reduce -> partial row (no atomics, no memset).
// ============================================================
__global__ __launch_bounds__(256)
void mid_half(const ushort* __restrict__ U, const float* __restrict__ Vs,
              float* __restrict__ Pout)
{
    __shared__ float sblk[NO * DOUT];     // swizzled: (o,d) at [o*32 + ((d+o)&31)]
    const int t    = threadIdx.x;
    const int bl   = blockIdx.x >> 5;
    const int iseg = blockIdx.x & 31;
    const int i0   = iseg * (NI / PSEG);

    for (int n = t; n < NO * DOUT; n += 256) sblk[n] = 0.f;

    const int lane = t & 63;
    const int o    = lane & 31;
    const int dh   = lane >> 5;       // d = dh*16 + ld
    const int wv   = t >> 6;          // wave 0..3 -> 16 i each (two streams of 8)

    float vs[16];
    {
        const float4* vp = (const float4*)(Vs + ((size_t)bl * NO + o) * DOUT + dh * 16);
        #pragma unroll
        for (int m = 0; m < 4; ++m) {
            float4 v = vp[m];
            vs[4*m+0] = v.x; vs[4*m+1] = v.y; vs[4*m+2] = v.z; vs[4*m+3] = v.w;
        }
    }

    float sacc[16];
    #pragma unroll
    for (int ld = 0; ld < 16; ++ld) sacc[ld] = 0.f;

    __syncthreads();   // sblk zero-init visible

    // per (bl,i): 4*NO u32x4; rows 2dh, 2dh+1 -> d = 16dh + (0..15)
    const u32x4* upA = (const u32x4*)U
        + (((size_t)bl * NI + i0 + wv * 16) * 4 + 2 * dh) * NO + o;
    const u32x4* upB = upA + (size_t)8 * 4 * NO;   // stream B: i+8

    u32x4 a0 = upA[0];
    u32x4 a1 = upA[NO];
    u32x4 b0 = upB[0];
    u32x4 b1 = upB[NO];
    upA += 4 * NO;
    upB += 4 * NO;

    for (int ii = 0; ii < 8; ++ii) {
        u32x4 na0 = {}, na1 = {}, nb0 = {}, nb1 = {};
        const bool more = (ii < 7);   // uniform
        if (more) {
            na0 = upA[0];
            na1 = upA[NO];
            nb0 = upB[0];
            nb1 = upB[NO];
            upA += 4 * NO;
            upB += 4 * NO;
        }

        mid_proc(a0, a1, vs, sacc);   // two independent chains -> 2x chain ILP
        mid_proc(b0, b1, vs, sacc);

        if (more) { a0 = na0; a1 = na1; b0 = nb0; b1 = nb1; }
    }

    // block reduce (swizzled -> <=2-way, free)
    #pragma unroll
    for (int ld = 0; ld < 16; ++ld) {
        const int d = dh * 16 + ld;
        atomicAdd(&sblk[o * 32 + ((d + o) & 31)], sacc[ld]);
    }
    __syncthreads();

    float* sp = Pout + ((size_t)(bl * PSEG + iseg)) * 1024;
    for (int n = t; n < NO * DOUT; n += 256) {
        const int oo = n >> 5, dd = n & 31;
        sp[n] = sblk[oo * 32 + ((dd + oo) & 31)];
    }
}

// ============================================================
// squash_final_half: reduce P2 partials, squash, write out for this half.
// ============================================================
__global__ __launch_bounds__(256)
void squash_final_half(const float* __restrict__ P2, float* __restrict__ out,
                       int b0)
{
    const int g    = blockIdx.x * 256 + threadIdx.x;   // bl*1024 + o*32 + d
    const int bl   = g >> 10, slot = g & 1023;
    float a = 0.f;
    for (int is = 0; is < PSEG; ++is)
        a += P2[((size_t)(bl * PSEG + is)) * 1024 + slot];

    float sq = a * a;
    #pragma unroll
    for (int msk = 16; msk >= 1; msk >>= 1) sq += __shfl_xor(sq, msk);
    const float sc = sq / (1.f + sq) * rsqrtf(sq + EPSQ);
    out[(size_t)(b0 + bl) * 1024 + slot] = a * sc;
}

// ============================================================
// FALLBACK PATH (fused recompute; used if ws too small)
// ============================================================
constexpr int BTILE  = 16;
constexpr int ITILE  = 32;
constexpr int CHUNKS = NI / ITILE;
constexpr int GB     = B_ / BTILE;
constexpr int WROW   = DOUT * DK + 4;

__global__ __launch_bounds__(512)
void routing_pass(const float* __restrict__ x, const float* __restrict__ W,
                  const float* __restrict__ Vsum, float* __restrict__ s_out)
{
    __shared__ float W_s[NO * WROW];
    const int tid   = threadIdx.x;
    const int o     = tid & 31;
    const int bl    = tid >> 5;
    const int chunk = blockIdx.x & (CHUNKS - 1);
    const int gb    = blockIdx.x / CHUNKS;
    const int b     = gb * BTILE + bl;

    float vs[DOUT];
    {
        const float4* vp = (const float4*)(Vsum + (size_t)(b * NO + o) * DOUT);
        #pragma unroll
        for (int qq = 0; qq < 8; ++qq) {
            float4 t2 = vp[qq];
            vs[4*qq+0] = t2.x; vs[4*qq+1] = t2.y; vs[4*qq+2] = t2.z; vs[4*qq+3] = t2.w;
        }
    }
    float sacc[DOUT];
    #pragma unroll
    for (int d = 0; d < DOUT; ++d) sacc[d] = 0.f;

    const int o_ld = tid >> 4;
    const int lpos = tid & 15;

    for (int ii = 0; ii < ITILE; ++ii) {
        const int i = chunk * ITILE + ii;
        __syncthreads();
        const float4* wsrc = (const float4*)W + ((size_t)o_ld * NI + i) * (DOUT * DK / 4);
        #pragma unroll
        for (int jj = 0; jj < 8; ++jj) {
            const int f4pos = lpos + 16 * jj;
            float4 v = wsrc[f4pos];
            *(float4*)&W_s[o_ld * WROW + f4pos * 4] = v;
        }
        __syncthreads();

        const float4* xg = (const float4*)(x + ((size_t)b * NI + i) * DK);
        const float4 xr0 = xg[0], xr1 = xg[1], xr2 = xg[2], xr3 = xg[3];

        float u[DOUT];
        float logit = 0.f;
        const float* wrow = &W_s[o * WROW];
        #pragma unroll
        for (int d = 0; d < DOUT; ++d) {
            const float4 w0 = *(const float4*)(wrow + d * DK + 0);
            const float4 w1 = *(const float4*)(wrow + d * DK + 4);
            const float4 w2 = *(const float4*)(wrow + d * DK + 8);
            const float4 w3 = *(const float4*)(wrow + d * DK + 12);
            float acc;
            acc  = w0.x * xr0.x + w0.y * xr0.y + w0.z * xr0.z + w0.w * xr0.w;
            acc += w1.x * xr1.x + w1.y * xr1.y + w1.z * xr1.z + w1.w * xr1.w;
            acc += w2.x * xr2.x + w2.y * xr2.y + w2.z * xr2.z + w2.w * xr2.w;
            acc += w3.x * xr3.x + w3.y * xr3.y + w3.z * xr3.z + w3.w * xr3.w;
            u[d]  = acc;
            logit = fmaf(vs[d], acc, logit);
        }

        float m = logit;
        #pragma unroll
        for (int msk = 16; msk >= 1; msk >>= 1) m = fmaxf(m, __shfl_xor(m, msk));
        const float e = __expf(logit - m);
        float ssum = e;
        #pragma unroll
        for (int msk = 16; msk >= 1; msk >>= 1) ssum += __shfl_xor(ssum, msk);
        const float c = e / ssum;

        #pragma unroll
        for (int d = 0; d < DOUT; ++d) sacc[d] = fmaf(c, u[d], sacc[d]);
    }

    float* sp = s_out + (size_t)(b * NO + o) * DOUT;
    #pragma unroll
    for (int d = 0; d < DOUT; ++d) atomicAdd(&sp[d], sacc[d]);
}

__global__ __launch_bounds__(256)
void squash_update(const float* __restrict__ s, float* __restrict__ Vsum,
                   float* __restrict__ out, int last)
{
    const int tid  = threadIdx.x;
    const int pair = blockIdx.x * 8 + (tid >> 5);
    const int d    = tid & 31;
    const int idx  = pair * DOUT + d;

    const float val = s[idx];
    float sq = val * val;
    #pragma unroll
    for (int msk = 16; msk >= 1; msk >>= 1) sq += __shfl_xor(sq, msk);

    const float scale = sq / (1.f + sq) * rsqrtf(sq + EPSQ);
    const float v = val * scale;

    if (last) out[idx] = v;
    else      Vsum[idx] += v;
}

// ============================================================
extern "C" void kernel_launch(void* const* d_in, const int* in_sizes, int n_in,
                              void* d_out, int out_size, void* d_ws, size_t ws_size,
                              hipStream_t stream)
{
    const float* x = (const float*)d_in[0];   // [B, NI, DK]
    const float* W = (const float*)d_in[1];   // [NO, NI, DOUT, DK]
    float* out = (float*)d_out;               // [B, NO, DOUT]

    const size_t VSB = (size_t)BH * 1024 * sizeof(float);          // 128 KB
    const size_t PB  = (size_t)BH * PSEG * 1024 * sizeof(float);   // 4 MB
    const size_t UHB = (size_t)BH * NI * NO * DOUT * sizeof(ushort); // 134 MB
    const size_t need_half = 2 * VSB + 3 * PB + UHB;               // ~146.5 MB

    if (ws_size >= need_half) {
        char* w = (char*)d_ws;
        float* Vs1 = (float*)w;                 w += VSB;
        float* Vs2 = (float*)w;                 w += VSB;
        float* P0  = (float*)w;                 w += PB;
        float* P1  = (float*)w;                 w += PB;
        float* P2  = (float*)w;                 w += PB;
        ushort* U  = (ushort*)w;

        for (int h = 0; h < 2; ++h) {
            const int b0 = h * BH;
            uhat_half<<<dim3(NI * 2), dim3(512), 0, stream>>>(x, W, U, b0);
            sum_u_half<<<dim3(BH * PSEG), dim3(256), 0, stream>>>(U, P0);
            rsq<1><<<dim3(BH * 1024 / 256), dim3(256), 0, stream>>>(P0, nullptr, Vs1);
            mid_half<<<dim3(BH * PSEG), dim3(256), 0, stream>>>(U, Vs1, P1);
            rsq<2><<<dim3(BH * 1024 / 256), dim3(256), 0, stream>>>(P1, Vs1, Vs2);
            mid_half<<<dim3(BH * PSEG), dim3(256), 0, stream>>>(U, Vs2, P2);
            squash_final_half<<<dim3(BH * 1024 / 256), dim3(256), 0, stream>>>(P2, out, b0);
        }
    } else {
        float* s0 = (float*)d_ws;
        float* s1 = s0 + (size_t)B_ * 1024;
        hipMemsetAsync(d_ws, 0, (size_t)2 * B_ * 1024 * sizeof(float), stream);
        for (int r = 0; r < 3; ++r) {
            if (r > 0)
                hipMemsetAsync(s0, 0, (size_t)B_ * 1024 * sizeof(float), stream);
            routing_pass<<<dim3(GB * CHUNKS), dim3(512), 0, stream>>>(x, W, s1, s0);
            squash_update<<<dim3(B_ * NO / 8), dim3(256), 0, stream>>>(s0, s1, out, r == 2);
        }
    }
}

// Round 8
// 477.140 us; speedup vs baseline: 1.5690x; 1.5690x over previous
//
#include <hip/hip_runtime.h>

#define B_    64
#define NI    2048
#define DK    16
#define NO    32
#define DOUT  32
#define EPSQ  1e-7f

typedef unsigned u32x2 __attribute__((ext_vector_type(2)));
typedef unsigned u32x4 __attribute__((ext_vector_type(4)));

constexpr int PSEG = 32;   // i-segments (partials + mid blocking)

// ---------- helpers ----------
__device__ __forceinline__ unsigned pack2_bf16(float a, float b) {
    unsigned ua = __float_as_uint(a);
    unsigned ub = __float_as_uint(b);
    ua = (ua + 0x7fffu + ((ua >> 16) & 1u)) >> 16;   // RNE
    ub = (ub + 0x7fffu + ((ub >> 16) & 1u)) >> 16;
    return ua | (ub << 16);
}
__device__ __forceinline__ float bf_lo(unsigned w) { return __uint_as_float(w << 16); }
__device__ __forceinline__ float bf_hi(unsigned w) { return __uint_as_float(w & 0xffff0000u); }

// ============================================================
// u_hat layout (bf16/ushort): idx = (((b*NI + i)*4 + j)*NO + o)*8 + e, d = j*8+e
// per (b,i): 4 rows of 256 ushorts = 2KB contiguous.
// ============================================================

// ------------------------------------------------------------
// compute_uhat: EXACT round-2/5 verified version (125 us, VGPR 56,
// 0 LDS conflicts). Block = one i, 512 threads, full B. No forced
// min-occupancy (round-4 lesson); regular W loads (round-7 lesson:
// NT W loads tanked VALUBusy 44->15%); no b-halving (round-7 lesson:
// halving repeats the 134 MB W stream per half).
// ------------------------------------------------------------
constexpr int WSTRIDE = 516;   // 512 + 4 pad

__global__ __launch_bounds__(512)
void compute_uhat(const float* __restrict__ x, const float* __restrict__ W,
                  ushort* __restrict__ U)
{
    __shared__ float Ws[NO * WSTRIDE];   // 66048 B
    __shared__ float xs[B_ * DK];        // 4096 B
    const int i = blockIdx.x;
    const int t = threadIdx.x;

    // stage x[0:64, i, 0:16] (4 KB)
    if (t < 256) {
        const int b = t >> 2, k4 = t & 3;
        float4 v = *(const float4*)(x + ((size_t)b * NI + i) * DK + k4 * 4);
        *(float4*)&xs[b * DK + k4 * 4] = v;
    }

    // stage W[:, i, :, :] (64 KB) coalesced
    #pragma unroll
    for (int jj = 0; jj < 8; ++jj) {
        const int p  = t + 512 * jj;     // 0..4095
        const int oo = p >> 7;           // o
        const int cc = p & 127;          // float4 within o-row
        float4 v = ((const float4*)(W + ((size_t)oo * NI + i) * (DOUT * DK)))[cc];
        *(float4*)&Ws[oo * WSTRIDE + cc * 4] = v;
    }

    const int o  = t & 31;
    const int q  = (t >> 5) & 7;      // d = 4q .. 4q+3
    const int bh = t >> 8;            // 0/1

    __syncthreads();

    // LDS -> regs: W[o,i,4q:4q+4,0:16] = 64 consecutive floats
    float w[64];
    {
        const float* wr = &Ws[o * WSTRIDE + q * 64];
        #pragma unroll
        for (int m = 0; m < 16; ++m) {
            float4 v = *(const float4*)(wr + 4 * m);
            w[4*m+0] = v.x; w[4*m+1] = v.y; w[4*m+2] = v.z; w[4*m+3] = v.w;
        }
    }

    const int j = q >> 1, half = q & 1;

    for (int bb = 0; bb < 32; ++bb) {
        const int b = bh * 32 + bb;
        const float4* xv = (const float4*)&xs[b * DK];
        const float4 x0 = xv[0], x1 = xv[1], x2 = xv[2], x3 = xv[3];

        float acc[4];
        #pragma unroll
        for (int dl = 0; dl < 4; ++dl) {
            const float* wr = &w[dl * 16];
            float a;
            a  = wr[0]  * x0.x + wr[1]  * x0.y + wr[2]  * x0.z + wr[3]  * x0.w;
            a += wr[4]  * x1.x + wr[5]  * x1.y + wr[6]  * x1.z + wr[7]  * x1.w;
            a += wr[8]  * x2.x + wr[9]  * x2.y + wr[10] * x2.z + wr[11] * x2.w;
            a += wr[12] * x3.x + wr[13] * x3.y + wr[14] * x3.z + wr[15] * x3.w;
            acc[dl] = a;
        }

        u32x2 pk;
        pk.x = pack2_bf16(acc[0], acc[1]);
        pk.y = pack2_bf16(acc[2], acc[3]);
        const size_t off = ((((size_t)b * NI + i) * 4 + j) * NO + o) * 8 + half * 4;
        __builtin_nontemporal_store(pk, (u32x2*)(U + off));   // 8-byte aligned
    }
}

// ============================================================
// sum_u: P0[b,iseg,o,d] = (1/32)*sum_{i in seg} u. Block = (b, iseg of 64 i).
// 256 threads; c = t&127 owns one uint4 column; i-parity halves; LDS merge;
// non-atomic partial row write. NT loads (U > L3, pure stream).
// ============================================================
__global__ __launch_bounds__(256)
void sum_u(const ushort* __restrict__ U, float* __restrict__ P0)
{
    __shared__ float red[128 * 9];     // pad 9 -> conflict-free
    const int t    = threadIdx.x;
    const int b    = blockIdx.x >> 5;
    const int iseg = blockIdx.x & 31;
    const int c    = t & 127;
    const int half = t >> 7;

    float acc[8];
    #pragma unroll
    for (int k = 0; k < 8; ++k) acc[k] = 0.f;

    const u32x4* up = (const u32x4*)U
        + ((size_t)b * NI + (size_t)iseg * (NI / PSEG) + half) * 128 + c;

    #pragma unroll 8
    for (int it = 0; it < (NI / PSEG) / 2; ++it) {
        u32x4 w = __builtin_nontemporal_load(up);
        up += 256;
        acc[0] += bf_lo(w.x); acc[1] += bf_hi(w.x);
        acc[2] += bf_lo(w.y); acc[3] += bf_hi(w.y);
        acc[4] += bf_lo(w.z); acc[5] += bf_hi(w.z);
        acc[6] += bf_lo(w.w); acc[7] += bf_hi(w.w);
    }

    if (half == 1) {
        #pragma unroll
        for (int k = 0; k < 8; ++k) red[c * 9 + k] = acc[k];
    }
    __syncthreads();
    if (half == 0) {
        #pragma unroll
        for (int k = 0; k < 8; ++k) acc[k] = (acc[k] + red[c * 9 + k]) * 0.03125f;

        const int o = c & 31, j = c >> 5;
        float* sp = P0 + ((size_t)(b * PSEG + iseg)) * 1024 + o * 32 + j * 8;
        float4 lo = {acc[0], acc[1], acc[2], acc[3]};
        float4 hi = {acc[4], acc[5], acc[6], acc[7]};
        *(float4*)sp = lo;
        *(float4*)(sp + 4) = hi;
    }
}

// ============================================================
// rsq: reduce partials -> s, squash -> v, accumulate running Vsum.
// R==1: VsOut = squash(sum P).  R==2: VsOut = VsIn + squash(sum P).
// Runs ONCE per round (256 blocks) -- removes the per-mid-block fan-in
// that cost 268/536 MB of redundant reads in round 5.
// ============================================================
template<int R>
__global__ __launch_bounds__(256)
void rsq(const float* __restrict__ P, const float* __restrict__ VsIn,
         float* __restrict__ VsOut)
{
    const int g  = blockIdx.x * 256 + threadIdx.x;   // b*1024 + o*32 + d
    const int b  = g >> 10, slot = g & 1023;
    float a = 0.f;
    for (int is = 0; is < PSEG; ++is)
        a += P[((size_t)(b * PSEG + is)) * 1024 + slot];

    float sq = a * a;
    #pragma unroll
    for (int msk = 16; msk >= 1; msk >>= 1) sq += __shfl_xor(sq, msk);
    const float sc = sq / (1.f + sq) * rsqrtf(sq + EPSQ);
    const float v  = a * sc;
    VsOut[g] = (R == 1) ? v : v + VsIn[g];
}

// ---------- per-i routing math: logit -> softmax over o -> accumulate ----------
__device__ __forceinline__ void mid_proc(const u32x4 c0, const u32x4 c1,
                                         const float* vs, float* sacc)
{
    float lp = 0.f;
    #pragma unroll
    for (int wi = 0; wi < 4; ++wi) {
        lp = fmaf(vs[2*wi],         bf_lo(c0[wi]), lp);
        lp = fmaf(vs[2*wi + 1],     bf_hi(c0[wi]), lp);
        lp = fmaf(vs[8 + 2*wi],     bf_lo(c1[wi]), lp);
        lp = fmaf(vs[8 + 2*wi + 1], bf_hi(c1[wi]), lp);
    }
    lp += __shfl_xor(lp, 32);    // full logit on all 64 lanes

    float mx = lp;
    #pragma unroll
    for (int msk = 16; msk >= 1; msk >>= 1) mx = fmaxf(mx, __shfl_xor(mx, msk));
    const float e = __expf(lp - mx);
    float ss = e;
    #pragma unroll
    for (int msk = 16; msk >= 1; msk >>= 1) ss += __shfl_xor(ss, msk);
    const float cc = e / ss;

    #pragma unroll
    for (int wi = 0; wi < 4; ++wi) {
        sacc[2*wi]         = fmaf(cc, bf_lo(c0[wi]), sacc[2*wi]);
        sacc[2*wi + 1]     = fmaf(cc, bf_hi(c0[wi]), sacc[2*wi + 1]);
        sacc[8 + 2*wi]     = fmaf(cc, bf_lo(c1[wi]), sacc[8 + 2*wi]);
        sacc[8 + 2*wi + 1] = fmaf(cc, bf_hi(c1[wi]), sacc[8 + 2*wi + 1]);
    }
}

// ============================================================
// mid: one routing pass over U. Block = (b, iseg of 64 i). 256 thr = 4 waves.
// One full wave per i (lane = o, dh); dual 8-i streams -> 2x chain ILP.
// Prologue: vs[16] = 4 float4 from precomputed Vs (16 KB/block, L2-hit).
// Epilogue: LDS-swizzled reduce -> non-atomic partial row.
// ============================================================
__global__ __launch_bounds__(256)
void mid(const ushort* __restrict__ U, const float* __restrict__ Vs,
         float* __restrict__ Pout)
{
    __shared__ float sblk[NO * DOUT];     // swizzled: (o,d) at [o*32 + ((d+o)&31)]
    const int t    = threadIdx.x;
    const int b    = blockIdx.x >> 5;
    const int iseg = blockIdx.x & 31;
    const int i0   = iseg * (NI / PSEG);

    for (int n = t; n < NO * DOUT; n += 256) sblk[n] = 0.f;

    const int lane = t & 63;
    const int o    = lane & 31;
    const int dh   = lane >> 5;       // d = dh*16 + ld
    const int wv   = t >> 6;          // wave 0..3 -> 16 i each (two streams of 8)

    float vs[16];
    {
        const float4* vp = (const float4*)(Vs + ((size_t)b * NO + o) * DOUT + dh * 16);
        #pragma unroll
        for (int m = 0; m < 4; ++m) {
            float4 v = vp[m];
            vs[4*m+0] = v.x; vs[4*m+1] = v.y; vs[4*m+2] = v.z; vs[4*m+3] = v.w;
        }
    }

    float sacc[16];
    #pragma unroll
    for (int ld = 0; ld < 16; ++ld) sacc[ld] = 0.f;

    __syncthreads();   // sblk zero-init visible

    // per (b,i): 4*NO u32x4; rows 2dh, 2dh+1 -> d = 16dh + (0..15)
    const u32x4* upA = (const u32x4*)U
        + (((size_t)b * NI + i0 + wv * 16) * 4 + 2 * dh) * NO + o;
    const u32x4* upB = upA + (size_t)8 * 4 * NO;   // stream B: i+8

    u32x4 a0 = __builtin_nontemporal_load(upA);
    u32x4 a1 = __builtin_nontemporal_load(upA + NO);
    u32x4 b0 = __builtin_nontemporal_load(upB);
    u32x4 b1 = __builtin_nontemporal_load(upB + NO);
    upA += 4 * NO;
    upB += 4 * NO;

    for (int ii = 0; ii < 8; ++ii) {
        u32x4 na0 = {}, na1 = {}, nb0 = {}, nb1 = {};
        const bool more = (ii < 7);   // uniform
        if (more) {
            na0 = __builtin_nontemporal_load(upA);
            na1 = __builtin_nontemporal_load(upA + NO);
            nb0 = __builtin_nontemporal_load(upB);
            nb1 = __builtin_nontemporal_load(upB + NO);
            upA += 4 * NO;
            upB += 4 * NO;
        }

        mid_proc(a0, a1, vs, sacc);   // two independent chains -> 2x chain ILP
        mid_proc(b0, b1, vs, sacc);

        if (more) { a0 = na0; a1 = na1; b0 = nb0; b1 = nb1; }
    }

    // block reduce (swizzled -> <=2-way, free)
    #pragma unroll
    for (int ld = 0; ld < 16; ++ld) {
        const int d = dh * 16 + ld;
        atomicAdd(&sblk[o * 32 + ((d + o) & 31)], sacc[ld]);
    }
    __syncthreads();

    float* sp = Pout + ((size_t)(b * PSEG + iseg)) * 1024;
    for (int n = t; n < NO * DOUT; n += 256) {
        const int oo = n >> 5, dd = n & 31;
        sp[n] = sblk[oo * 32 + ((dd + oo) & 31)];
    }
}

// ============================================================
// squash_final: reduce P2 partials, squash, write out.
// ============================================================
__global__ __launch_bounds__(256)
void squash_final(const float* __restrict__ P2, float* __restrict__ out)
{
    const int g  = blockIdx.x * 256 + threadIdx.x;   // b*1024 + o*32 + d
    const int b  = g >> 10, slot = g & 1023;
    float a = 0.f;
    for (int is = 0; is < PSEG; ++is)
        a += P2[((size_t)(b * PSEG + is)) * 1024 + slot];

    float sq = a * a;
    #pragma unroll
    for (int msk = 16; msk >= 1; msk >>= 1) sq += __shfl_xor(sq, msk);
    const float sc = sq / (1.f + sq) * rsqrtf(sq + EPSQ);
    out[g] = a * sc;
}

// ============================================================
// FALLBACK PATH (fused recompute; used if ws too small)
// ============================================================
constexpr int BTILE  = 16;
constexpr int ITILE  = 32;
constexpr int CHUNKS = NI / ITILE;
constexpr int GB     = B_ / BTILE;
constexpr int WROW   = DOUT * DK + 4;

__global__ __launch_bounds__(512)
void routing_pass(const float* __restrict__ x, const float* __restrict__ W,
                  const float* __restrict__ Vsum, float* __restrict__ s_out)
{
    __shared__ float W_s[NO * WROW];
    const int tid   = threadIdx.x;
    const int o     = tid & 31;
    const int bl    = tid >> 5;
    const int chunk = blockIdx.x & (CHUNKS - 1);
    const int gb    = blockIdx.x / CHUNKS;
    const int b     = gb * BTILE + bl;

    float vs[DOUT];
    {
        const float4* vp = (const float4*)(Vsum + (size_t)(b * NO + o) * DOUT);
        #pragma unroll
        for (int qq = 0; qq < 8; ++qq) {
            float4 t2 = vp[qq];
            vs[4*qq+0] = t2.x; vs[4*qq+1] = t2.y; vs[4*qq+2] = t2.z; vs[4*qq+3] = t2.w;
        }
    }
    float sacc[DOUT];
    #pragma unroll
    for (int d = 0; d < DOUT; ++d) sacc[d] = 0.f;

    const int o_ld = tid >> 4;
    const int lpos = tid & 15;

    for (int ii = 0; ii < ITILE; ++ii) {
        const int i = chunk * ITILE + ii;
        __syncthreads();
        const float4* wsrc = (const float4*)W + ((size_t)o_ld * NI + i) * (DOUT * DK / 4);
        #pragma unroll
        for (int jj = 0; jj < 8; ++jj) {
            const int f4pos = lpos + 16 * jj;
            float4 v = wsrc[f4pos];
            *(float4*)&W_s[o_ld * WROW + f4pos * 4] = v;
        }
        __syncthreads();

        const float4* xg = (const float4*)(x + ((size_t)b * NI + i) * DK);
        const float4 xr0 = xg[0], xr1 = xg[1], xr2 = xg[2], xr3 = xg[3];

        float u[DOUT];
        float logit = 0.f;
        const float* wrow = &W_s[o * WROW];
        #pragma unroll
        for (int d = 0; d < DOUT; ++d) {
            const float4 w0 = *(const float4*)(wrow + d * DK + 0);
            const float4 w1 = *(const float4*)(wrow + d * DK + 4);
            const float4 w2 = *(const float4*)(wrow + d * DK + 8);
            const float4 w3 = *(const float4*)(wrow + d * DK + 12);
            float acc;
            acc  = w0.x * xr0.x + w0.y * xr0.y + w0.z * xr0.z + w0.w * xr0.w;
            acc += w1.x * xr1.x + w1.y * xr1.y + w1.z * xr1.z + w1.w * xr1.w;
            acc += w2.x * xr2.x + w2.y * xr2.y + w2.z * xr2.z + w2.w * xr2.w;
            acc += w3.x * xr3.x + w3.y * xr3.y + w3.z * xr3.z + w3.w * xr3.w;
            u[d]  = acc;
            logit = fmaf(vs[d], acc, logit);
        }

        float m = logit;
        #pragma unroll
        for (int msk = 16; msk >= 1; msk >>= 1) m = fmaxf(m, __shfl_xor(m, msk));
        const float e = __expf(logit - m);
        float ssum = e;
        #pragma unroll
        for (int msk = 16; msk >= 1; msk >>= 1) ssum += __shfl_xor(ssum, msk);
        const float c = e / ssum;

        #pragma unroll
        for (int d = 0; d < DOUT; ++d) sacc[d] = fmaf(c, u[d], sacc[d]);
    }

    float* sp = s_out + (size_t)(b * NO + o) * DOUT;
    #pragma unroll
    for (int d = 0; d < DOUT; ++d) atomicAdd(&sp[d], sacc[d]);
}

__global__ __launch_bounds__(256)
void squash_update(const float* __restrict__ s, float* __restrict__ Vsum,
                   float* __restrict__ out, int last)
{
    const int tid  = threadIdx.x;
    const int pair = blockIdx.x * 8 + (tid >> 5);
    const int d    = tid & 31;
    const int idx  = pair * DOUT + d;

    const float val = s[idx];
    float sq = val * val;
    #pragma unroll
    for (int msk = 16; msk >= 1; msk >>= 1) sq += __shfl_xor(sq, msk);

    const float scale = sq / (1.f + sq) * rsqrtf(sq + EPSQ);
    const float v = val * scale;

    if (last) out[idx] = v;
    else      Vsum[idx] += v;
}

// ============================================================
extern "C" void kernel_launch(void* const* d_in, const int* in_sizes, int n_in,
                              void* d_out, int out_size, void* d_ws, size_t ws_size,
                              hipStream_t stream)
{
    const float* x = (const float*)d_in[0];   // [B, NI, DK]
    const float* W = (const float*)d_in[1];   // [NO, NI, DOUT, DK]
    float* out = (float*)d_out;               // [B, NO, DOUT]

    const size_t VSB    = (size_t)B_ * 1024 * sizeof(float);            // 256 KB
    const size_t PB     = (size_t)B_ * PSEG * 1024 * sizeof(float);     // 8 MB
    const size_t UBYTES = (size_t)B_ * NI * NO * DOUT * sizeof(ushort); // 268 MB
    const size_t need   = 2 * VSB + 3 * PB + UBYTES;                    // ~293 MB

    if (ws_size >= need) {
        char* w = (char*)d_ws;
        float* Vs1 = (float*)w;                 w += VSB;
        float* Vs2 = (float*)w;                 w += VSB;
        float* P0  = (float*)w;                 w += PB;
        float* P1  = (float*)w;                 w += PB;
        float* P2  = (float*)w;                 w += PB;
        ushort* U  = (ushort*)w;

        compute_uhat<<<dim3(NI), dim3(512), 0, stream>>>(x, W, U);
        sum_u<<<dim3(B_ * PSEG), dim3(256), 0, stream>>>(U, P0);
        rsq<1><<<dim3(B_ * 1024 / 256), dim3(256), 0, stream>>>(P0, nullptr, Vs1);
        mid<<<dim3(B_ * PSEG), dim3(256), 0, stream>>>(U, Vs1, P1);
        rsq<2><<<dim3(B_ * 1024 / 256), dim3(256), 0, stream>>>(P1, Vs1, Vs2);
        mid<<<dim3(B_ * PSEG), dim3(256), 0, stream>>>(U, Vs2, P2);
        squash_final<<<dim3(B_ * 1024 / 256), dim3(256), 0, stream>>>(P2, out);
    } else {
        float* s0 = (float*)d_ws;
        float* s1 = s0 + (size_t)B_ * 1024;
        hipMemsetAsync(d_ws, 0, (size_t)2 * B_ * 1024 * sizeof(float), stream);
        for (int r = 0; r < 3; ++r) {
            if (r > 0)
                hipMemsetAsync(s0, 0, (size_t)B_ * 1024 * sizeof(float), stream);
            routing_pass<<<dim3(GB * CHUNKS), dim3(512), 0, stream>>>(x, W, s1, s0);
            squash_update<<<dim3(B_ * NO / 8), dim3(256), 0, stream>>>(s0, s1, out, r == 2);
        }
    }
}

// Round 9
// 431.561 us; speedup vs baseline: 1.7347x; 1.1056x over previous
//
#include <hip/hip_runtime.h>

#define B_    64
#define NI    2048
#define DK    16
#define NO    32
#define DOUT  32
#define EPSQ  1e-7f

typedef unsigned u32x2 __attribute__((ext_vector_type(2)));
typedef unsigned u32x4 __attribute__((ext_vector_type(4)));

constexpr int PSEG = 16;   // i-segments (partials + streaming-pass blocking)

// ---------- helpers ----------
__device__ __forceinline__ unsigned pack2_bf16(float a, float b) {
    unsigned ua = __float_as_uint(a);
    unsigned ub = __float_as_uint(b);
    ua = (ua + 0x7fffu + ((ua >> 16) & 1u)) >> 16;   // RNE
    ub = (ub + 0x7fffu + ((ub >> 16) & 1u)) >> 16;
    return ua | (ub << 16);
}
__device__ __forceinline__ float bf_lo(unsigned w) { return __uint_as_float(w << 16); }
__device__ __forceinline__ float bf_hi(unsigned w) { return __uint_as_float(w & 0xffff0000u); }

// ============================================================
// u_hat layout (bf16/ushort): idx = (((b*NI + i)*4 + j)*NO + o)*8 + e, d = j*8+e
// per (b,i): 4 rows of 256 ushorts = 2KB contiguous; 128 u32x4, u32x4 idx = j*NO+o.
// ============================================================

// ------------------------------------------------------------
// compute_uhat: EXACT round-2/5/8 verified version (124-131 us, VGPR 56,
// 0 LDS conflicts). Block = one i, 512 threads, full B.
// ------------------------------------------------------------
constexpr int WSTRIDE = 516;   // 512 + 4 pad

__global__ __launch_bounds__(512)
void compute_uhat(const float* __restrict__ x, const float* __restrict__ W,
                  ushort* __restrict__ U)
{
    __shared__ float Ws[NO * WSTRIDE];   // 66048 B
    __shared__ float xs[B_ * DK];        // 4096 B
    const int i = blockIdx.x;
    const int t = threadIdx.x;

    // stage x[0:64, i, 0:16] (4 KB)
    if (t < 256) {
        const int b = t >> 2, k4 = t & 3;
        float4 v = *(const float4*)(x + ((size_t)b * NI + i) * DK + k4 * 4);
        *(float4*)&xs[b * DK + k4 * 4] = v;
    }

    // stage W[:, i, :, :] (64 KB) coalesced
    #pragma unroll
    for (int jj = 0; jj < 8; ++jj) {
        const int p  = t + 512 * jj;     // 0..4095
        const int oo = p >> 7;           // o
        const int cc = p & 127;          // float4 within o-row
        float4 v = ((const float4*)(W + ((size_t)oo * NI + i) * (DOUT * DK)))[cc];
        *(float4*)&Ws[oo * WSTRIDE + cc * 4] = v;
    }

    const int o  = t & 31;
    const int q  = (t >> 5) & 7;      // d = 4q .. 4q+3
    const int bh = t >> 8;            // 0/1

    __syncthreads();

    // LDS -> regs: W[o,i,4q:4q+4,0:16] = 64 consecutive floats
    float w[64];
    {
        const float* wr = &Ws[o * WSTRIDE + q * 64];
        #pragma unroll
        for (int m = 0; m < 16; ++m) {
            float4 v = *(const float4*)(wr + 4 * m);
            w[4*m+0] = v.x; w[4*m+1] = v.y; w[4*m+2] = v.z; w[4*m+3] = v.w;
        }
    }

    const int j = q >> 1, half = q & 1;

    for (int bb = 0; bb < 32; ++bb) {
        const int b = bh * 32 + bb;
        const float4* xv = (const float4*)&xs[b * DK];
        const float4 x0 = xv[0], x1 = xv[1], x2 = xv[2], x3 = xv[3];

        float acc[4];
        #pragma unroll
        for (int dl = 0; dl < 4; ++dl) {
            const float* wr = &w[dl * 16];
            float a;
            a  = wr[0]  * x0.x + wr[1]  * x0.y + wr[2]  * x0.z + wr[3]  * x0.w;
            a += wr[4]  * x1.x + wr[5]  * x1.y + wr[6]  * x1.z + wr[7]  * x1.w;
            a += wr[8]  * x2.x + wr[9]  * x2.y + wr[10] * x2.z + wr[11] * x2.w;
            a += wr[12] * x3.x + wr[13] * x3.y + wr[14] * x3.z + wr[15] * x3.w;
            acc[dl] = a;
        }

        u32x2 pk;
        pk.x = pack2_bf16(acc[0], acc[1]);
        pk.y = pack2_bf16(acc[2], acc[3]);
        const size_t off = ((((size_t)b * NI + i) * 4 + j) * NO + o) * 8 + half * 4;
        __builtin_nontemporal_store(pk, (u32x2*)(U + off));   // 8-byte aligned
    }
}

// ============================================================
// sum_u: P0[b,seg,o,d] = (1/32)*sum_{i in seg} u. Block = (b, seg of 128 i).
// 256 threads; c = t&127 owns one uint4 column; half = t>>7 covers 64 i.
// 4 independent loads per iteration (64 B/thread in flight vs 16 B in r8).
// LDS half-merge, non-atomic partial row write. NT loads (U > L3).
// ============================================================
__global__ __launch_bounds__(256)
void sum_u(const ushort* __restrict__ U, float* __restrict__ P0)
{
    __shared__ float red[128 * 9];     // pad 9 -> conflict-free
    const int t    = threadIdx.x;
    const int b    = blockIdx.x >> 4;
    const int seg  = blockIdx.x & 15;
    const int c    = t & 127;
    const int half = t >> 7;

    float acc[8];
    #pragma unroll
    for (int k = 0; k < 8; ++k) acc[k] = 0.f;

    // i-range for this thread: seg*128 + half*64 .. +63, 4 i per iteration
    const u32x4* up = (const u32x4*)U
        + ((size_t)b * NI + (size_t)seg * 128 + half * 64) * 128 + c;

    for (int it = 0; it < 16; ++it) {
        u32x4 w0 = __builtin_nontemporal_load(up);
        u32x4 w1 = __builtin_nontemporal_load(up + 128);
        u32x4 w2 = __builtin_nontemporal_load(up + 256);
        u32x4 w3 = __builtin_nontemporal_load(up + 384);
        up += 512;
        acc[0] += bf_lo(w0.x); acc[1] += bf_hi(w0.x);
        acc[2] += bf_lo(w0.y); acc[3] += bf_hi(w0.y);
        acc[4] += bf_lo(w0.z); acc[5] += bf_hi(w0.z);
        acc[6] += bf_lo(w0.w); acc[7] += bf_hi(w0.w);
        acc[0] += bf_lo(w1.x); acc[1] += bf_hi(w1.x);
        acc[2] += bf_lo(w1.y); acc[3] += bf_hi(w1.y);
        acc[4] += bf_lo(w1.z); acc[5] += bf_hi(w1.z);
        acc[6] += bf_lo(w1.w); acc[7] += bf_hi(w1.w);
        acc[0] += bf_lo(w2.x); acc[1] += bf_hi(w2.x);
        acc[2] += bf_lo(w2.y); acc[3] += bf_hi(w2.y);
        acc[4] += bf_lo(w2.z); acc[5] += bf_hi(w2.z);
        acc[6] += bf_lo(w2.w); acc[7] += bf_hi(w2.w);
        acc[0] += bf_lo(w3.x); acc[1] += bf_hi(w3.x);
        acc[2] += bf_lo(w3.y); acc[3] += bf_hi(w3.y);
        acc[4] += bf_lo(w3.z); acc[5] += bf_hi(w3.z);
        acc[6] += bf_lo(w3.w); acc[7] += bf_hi(w3.w);
    }

    if (half == 1) {
        #pragma unroll
        for (int k = 0; k < 8; ++k) red[c * 9 + k] = acc[k];
    }
    __syncthreads();
    if (half == 0) {
        #pragma unroll
        for (int k = 0; k < 8; ++k) acc[k] = (acc[k] + red[c * 9 + k]) * 0.03125f;

        const int o = c & 31, j = c >> 5;
        float* sp = P0 + ((size_t)(b * PSEG + seg)) * 1024 + o * 32 + j * 8;
        float4 lo = {acc[0], acc[1], acc[2], acc[3]};
        float4 hi = {acc[4], acc[5], acc[6], acc[7]};
        *(float4*)sp = lo;
        *(float4*)(sp + 4) = hi;
    }
}

// ============================================================
// rsq: reduce partials -> s, squash -> v, accumulate running Vsum.
// R==1: VsOut = squash(sum P).  R==2: VsOut = VsIn + squash(sum P).
// ============================================================
template<int R>
__global__ __launch_bounds__(256)
void rsq(const float* __restrict__ P, const float* __restrict__ VsIn,
         float* __restrict__ VsOut)
{
    const int g  = blockIdx.x * 256 + threadIdx.x;   // b*1024 + o*32 + d
    const int b  = g >> 10, slot = g & 1023;
    float a = 0.f;
    #pragma unroll
    for (int is = 0; is < PSEG; ++is)
        a += P[((size_t)(b * PSEG + is)) * 1024 + slot];

    float sq = a * a;
    #pragma unroll
    for (int msk = 16; msk >= 1; msk >>= 1) sq += __shfl_xor(sq, msk);
    const float sc = sq / (1.f + sq) * rsqrtf(sq + EPSQ);
    const float v  = a * sc;
    VsOut[g] = (R == 1) ? v : v + VsIn[g];
}

// ---------- per-i routing math on 4 uint4 rows (round-0 proven structure) ----------
__device__ __forceinline__ void proc_i(const u32x4* cr, const float* vs, float* sacc)
{
    unsigned cw[16];
    #pragma unroll
    for (int jj = 0; jj < 4; ++jj) {
        cw[4*jj+0] = cr[jj].x; cw[4*jj+1] = cr[jj].y;
        cw[4*jj+2] = cr[jj].z; cw[4*jj+3] = cr[jj].w;
    }

    float l0 = 0.f, l1 = 0.f, l2 = 0.f, l3 = 0.f;
    #pragma unroll
    for (int m = 0; m < 16; m += 4) {
        const int d0 = (m >> 2) * 8;
        l0 = fmaf(vs[d0+0], bf_lo(cw[m+0]), l0);
        l0 = fmaf(vs[d0+1], bf_hi(cw[m+0]), l0);
        l1 = fmaf(vs[d0+2], bf_lo(cw[m+1]), l1);
        l1 = fmaf(vs[d0+3], bf_hi(cw[m+1]), l1);
        l2 = fmaf(vs[d0+4], bf_lo(cw[m+2]), l2);
        l2 = fmaf(vs[d0+5], bf_hi(cw[m+2]), l2);
        l3 = fmaf(vs[d0+6], bf_lo(cw[m+3]), l3);
        l3 = fmaf(vs[d0+7], bf_hi(cw[m+3]), l3);
    }
    const float logit = (l0 + l1) + (l2 + l3);

    // softmax over o = 32 lanes of this half-wave (xor masks <32 stay in-half)
    float mx = logit;
    #pragma unroll
    for (int msk = 16; msk >= 1; msk >>= 1) mx = fmaxf(mx, __shfl_xor(mx, msk));
    const float e = __expf(logit - mx);
    float ssum = e;
    #pragma unroll
    for (int msk = 16; msk >= 1; msk >>= 1) ssum += __shfl_xor(ssum, msk);
    const float c = e / ssum;

    #pragma unroll
    for (int m = 0; m < 16; ++m) {
        const int d0 = (m >> 2) * 8 + (m & 3) * 2;
        sacc[d0]     = fmaf(c, bf_lo(cw[m]), sacc[d0]);
        sacc[d0 + 1] = fmaf(c, bf_hi(cw[m]), sacc[d0 + 1]);
    }
}

// ============================================================
// mid: one routing pass (round-0 routing_stream structure — the fastest
// measured U-pass — with r8 plumbing: Vs precomputed, partial-row output).
// Block = (b, seg of 128 i). 256 thr = 8 half-waves; lane = o.
// Each half-wave: 2 consecutive i per iter, depth-1 group prefetch
// (cur[8]/nxt[8] = 128 B/thread in flight).
// ============================================================
__global__ __launch_bounds__(256)
void mid(const ushort* __restrict__ U, const float* __restrict__ Vs,
         float* __restrict__ Pout)
{
    __shared__ float sblk[NO * DOUT];   // swizzled: (o,d) at [o*32 + ((d+o)&31)]
    const int t   = threadIdx.x;
    const int b   = blockIdx.x >> 4;
    const int seg = blockIdx.x & 15;
    const int i0  = seg * (NI / PSEG);  // 128 i per block
    const int o   = t & 31;
    const int hw  = t >> 5;             // 0..7

    for (int n = t; n < NO * DOUT; n += 256) sblk[n] = 0.f;

    float vs[DOUT];
    {
        const float4* vp = (const float4*)(Vs + ((size_t)b * NO + o) * DOUT);
        #pragma unroll
        for (int m = 0; m < 8; ++m) {
            float4 v = vp[m];
            vs[4*m+0] = v.x; vs[4*m+1] = v.y; vs[4*m+2] = v.z; vs[4*m+3] = v.w;
        }
    }
    float sacc[DOUT];
    #pragma unroll
    for (int d = 0; d < DOUT; ++d) sacc[d] = 0.f;

    __syncthreads();   // sblk zero-init visible

    // per (b,i): 4*NO u32x4; row j at [j*NO]; i+1 is +4*NO
    const u32x4* up = (const u32x4*)U + ((size_t)b * NI + i0 + 2 * hw) * (4 * NO) + o;
    const size_t step = (size_t)16 * 4 * NO;   // advance i by 16

    u32x4 cur[8];
    #pragma unroll
    for (int jj = 0; jj < 4; ++jj) {
        cur[jj]     = __builtin_nontemporal_load(up + jj * NO);
        cur[4 + jj] = __builtin_nontemporal_load(up + 4 * NO + jj * NO);
    }
    up += step;

    for (int ii = 0; ii < 8; ++ii) {          // 8 groups x 16 i = 128 i
        u32x4 nxt[8] = {};
        const bool more = (ii < 7);           // uniform
        if (more) {
            #pragma unroll
            for (int jj = 0; jj < 4; ++jj) {
                nxt[jj]     = __builtin_nontemporal_load(up + jj * NO);
                nxt[4 + jj] = __builtin_nontemporal_load(up + 4 * NO + jj * NO);
            }
            up += step;
        }

        proc_i(&cur[0], vs, sacc);
        proc_i(&cur[4], vs, sacc);

        if (more) {
            #pragma unroll
            for (int jj = 0; jj < 8; ++jj) cur[jj] = nxt[jj];
        }
    }

    // reduce the wave's two half-waves (same (b,o), disjoint i)
    #pragma unroll
    for (int d = 0; d < DOUT; ++d) sacc[d] += __shfl_xor(sacc[d], 32);

    if ((t & 32) == 0) {
        #pragma unroll
        for (int d = 0; d < DOUT; ++d)
            atomicAdd(&sblk[o * 32 + ((d + o) & 31)], sacc[d]);  // conflict-free
    }
    __syncthreads();

    float* sp = Pout + ((size_t)(b * PSEG + seg)) * 1024;
    for (int n = t; n < NO * DOUT; n += 256) {
        const int oo = n >> 5, dd = n & 31;
        sp[n] = sblk[oo * 32 + ((dd + oo) & 31)];
    }
}

// ============================================================
// squash_final: reduce P2 partials, squash, write out.
// ============================================================
__global__ __launch_bounds__(256)
void squash_final(const float* __restrict__ P2, float* __restrict__ out)
{
    const int g  = blockIdx.x * 256 + threadIdx.x;   // b*1024 + o*32 + d
    const int b  = g >> 10, slot = g & 1023;
    float a = 0.f;
    #pragma unroll
    for (int is = 0; is < PSEG; ++is)
        a += P2[((size_t)(b * PSEG + is)) * 1024 + slot];

    float sq = a * a;
    #pragma unroll
    for (int msk = 16; msk >= 1; msk >>= 1) sq += __shfl_xor(sq, msk);
    const float sc = sq / (1.f + sq) * rsqrtf(sq + EPSQ);
    out[g] = a * sc;
}

// ============================================================
// FALLBACK PATH (fused recompute; used if ws too small)
// ============================================================
constexpr int BTILE  = 16;
constexpr int ITILE  = 32;
constexpr int CHUNKS = NI / ITILE;
constexpr int GB     = B_ / BTILE;
constexpr int WROW   = DOUT * DK + 4;

__global__ __launch_bounds__(512)
void routing_pass(const float* __restrict__ x, const float* __restrict__ W,
                  const float* __restrict__ Vsum, float* __restrict__ s_out)
{
    __shared__ float W_s[NO * WROW];
    const int tid   = threadIdx.x;
    const int o     = tid & 31;
    const int bl    = tid >> 5;
    const int chunk = blockIdx.x & (CHUNKS - 1);
    const int gb    = blockIdx.x / CHUNKS;
    const int b     = gb * BTILE + bl;

    float vs[DOUT];
    {
        const float4* vp = (const float4*)(Vsum + (size_t)(b * NO + o) * DOUT);
        #pragma unroll
        for (int qq = 0; qq < 8; ++qq) {
            float4 t2 = vp[qq];
            vs[4*qq+0] = t2.x; vs[4*qq+1] = t2.y; vs[4*qq+2] = t2.z; vs[4*qq+3] = t2.w;
        }
    }
    float sacc[DOUT];
    #pragma unroll
    for (int d = 0; d < DOUT; ++d) sacc[d] = 0.f;

    const int o_ld = tid >> 4;
    const int lpos = tid & 15;

    for (int ii = 0; ii < ITILE; ++ii) {
        const int i = chunk * ITILE + ii;
        __syncthreads();
        const float4* wsrc = (const float4*)W + ((size_t)o_ld * NI + i) * (DOUT * DK / 4);
        #pragma unroll
        for (int jj = 0; jj < 8; ++jj) {
            const int f4pos = lpos + 16 * jj;
            float4 v = wsrc[f4pos];
            *(float4*)&W_s[o_ld * WROW + f4pos * 4] = v;
        }
        __syncthreads();

        const float4* xg = (const float4*)(x + ((size_t)b * NI + i) * DK);
        const float4 xr0 = xg[0], xr1 = xg[1], xr2 = xg[2], xr3 = xg[3];

        float u[DOUT];
        float logit = 0.f;
        const float* wrow = &W_s[o * WROW];
        #pragma unroll
        for (int d = 0; d < DOUT; ++d) {
            const float4 w0 = *(const float4*)(wrow + d * DK + 0);
            const float4 w1 = *(const float4*)(wrow + d * DK + 4);
            const float4 w2 = *(const float4*)(wrow + d * DK + 8);
            const float4 w3 = *(const float4*)(wrow + d * DK + 12);
            float acc;
            acc  = w0.x * xr0.x + w0.y * xr0.y + w0.z * xr0.z + w0.w * xr0.w;
            acc += w1.x * xr1.x + w1.y * xr1.y + w1.z * xr1.z + w1.w * xr1.w;
            acc += w2.x * xr2.x + w2.y * xr2.y + w2.z * xr2.z + w2.w * xr2.w;
            acc += w3.x * xr3.x + w3.y * xr3.y + w3.z * xr3.z + w3.w * xr3.w;
            u[d]  = acc;
            logit = fmaf(vs[d], acc, logit);
        }

        float m = logit;
        #pragma unroll
        for (int msk = 16; msk >= 1; msk >>= 1) m = fmaxf(m, __shfl_xor(m, msk));
        const float e = __expf(logit - m);
        float ssum = e;
        #pragma unroll
        for (int msk = 16; msk >= 1; msk >>= 1) ssum += __shfl_xor(ssum, msk);
        const float c = e / ssum;

        #pragma unroll
        for (int d = 0; d < DOUT; ++d) sacc[d] = fmaf(c, u[d], sacc[d]);
    }

    float* sp = s_out + (size_t)(b * NO + o) * DOUT;
    #pragma unroll
    for (int d = 0; d < DOUT; ++d) atomicAdd(&sp[d], sacc[d]);
}

__global__ __launch_bounds__(256)
void squash_update(const float* __restrict__ s, float* __restrict__ Vsum,
                   float* __restrict__ out, int last)
{
    const int tid  = threadIdx.x;
    const int pair = blockIdx.x * 8 + (tid >> 5);
    const int d    = tid & 31;
    const int idx  = pair * DOUT + d;

    const float val = s[idx];
    float sq = val * val;
    #pragma unroll
    for (int msk = 16; msk >= 1; msk >>= 1) sq += __shfl_xor(sq, msk);

    const float scale = sq / (1.f + sq) * rsqrtf(sq + EPSQ);
    const float v = val * scale;

    if (last) out[idx] = v;
    else      Vsum[idx] += v;
}

// ============================================================
extern "C" void kernel_launch(void* const* d_in, const int* in_sizes, int n_in,
                              void* d_out, int out_size, void* d_ws, size_t ws_size,
                              hipStream_t stream)
{
    const float* x = (const float*)d_in[0];   // [B, NI, DK]
    const float* W = (const float*)d_in[1];   // [NO, NI, DOUT, DK]
    float* out = (float*)d_out;               // [B, NO, DOUT]

    const size_t VSB    = (size_t)B_ * 1024 * sizeof(float);            // 256 KB
    const size_t PB     = (size_t)B_ * PSEG * 1024 * sizeof(float);     // 4 MB
    const size_t UBYTES = (size_t)B_ * NI * NO * DOUT * sizeof(ushort); // 268 MB
    const size_t need   = 2 * VSB + 3 * PB + UBYTES;                    // ~281 MB

    if (ws_size >= need) {
        char* w = (char*)d_ws;
        float* Vs1 = (float*)w;                 w += VSB;
        float* Vs2 = (float*)w;                 w += VSB;
        float* P0  = (float*)w;                 w += PB;
        float* P1  = (float*)w;                 w += PB;
        float* P2  = (float*)w;                 w += PB;
        ushort* U  = (ushort*)w;

        compute_uhat<<<dim3(NI), dim3(512), 0, stream>>>(x, W, U);
        sum_u<<<dim3(B_ * PSEG), dim3(256), 0, stream>>>(U, P0);
        rsq<1><<<dim3(B_ * 1024 / 256), dim3(256), 0, stream>>>(P0, nullptr, Vs1);
        mid<<<dim3(B_ * PSEG), dim3(256), 0, stream>>>(U, Vs1, P1);
        rsq<2><<<dim3(B_ * 1024 / 256), dim3(256), 0, stream>>>(P1, Vs1, Vs2);
        mid<<<dim3(B_ * PSEG), dim3(256), 0, stream>>>(U, Vs2, P2);
        squash_final<<<dim3(B_ * 1024 / 256), dim3(256), 0, stream>>>(P2, out);
    } else {
        float* s0 = (float*)d_ws;
        float* s1 = s0 + (size_t)B_ * 1024;
        hipMemsetAsync(d_ws, 0, (size_t)2 * B_ * 1024 * sizeof(float), stream);
        for (int r = 0; r < 3; ++r) {
            if (r > 0)
                hipMemsetAsync(s0, 0, (size_t)B_ * 1024 * sizeof(float), stream);
            routing_pass<<<dim3(GB * CHUNKS), dim3(512), 0, stream>>>(x, W, s1, s0);
            squash_update<<<dim3(B_ * NO / 8), dim3(256), 0, stream>>>(s0, s1, out, r == 2);
        }
    }
}